// Round 8
// baseline (1716.807 us; speedup 1.0000x reference)
//
#include <hip/hip_runtime.h>
#include <hip/hip_bf16.h>
#include <math.h>

#define D_   512
#define H_   8
#define HD_  64
#define L_   6
#define FF_  2048
#define IN_  32
#define OUT_ 3
#define S_   512
#define B_   32
#define M_   (B_ * S_)   // 16384 token rows

typedef __attribute__((ext_vector_type(8))) short short8;
typedef __attribute__((ext_vector_type(4))) float floatx4;

// Branchless gelu: 0.5x(1+erf(x/sqrt2)), erf via A&S 7.1.26 (max err 1.5e-7).
__device__ __forceinline__ float gelu_f(float x) {
    const float ax = fabsf(x) * 0.70710678118654752f;
    const float t = __builtin_amdgcn_rcpf(fmaf(0.3275911f, ax, 1.0f));
    float p = fmaf(1.061405429f, t, -1.453152027f);
    p = fmaf(p, t, 1.421413741f);
    p = fmaf(p, t, -0.284496736f);
    p = fmaf(p, t, 0.254829592f);
    p = p * t;
    const float e = __expf(-ax * ax);
    const float er = copysignf(fmaf(-p, e, 1.0f), x);
    return 0.5f * x * (1.0f + er);
}
__device__ __forceinline__ float bf2f(unsigned short u) {
    union { unsigned int i; float f; } c; c.i = ((unsigned)u) << 16; return c.f;
}
__device__ __forceinline__ unsigned short f2bf(float v) {
    __hip_bfloat16 t = __float2bfloat16(v);
    return *(unsigned short*)&t;
}
__device__ __forceinline__ void async16(const void* g, void* l) {
    __builtin_amdgcn_global_load_lds(
        (const __attribute__((address_space(1))) unsigned int*)g,
        (__attribute__((address_space(3))) unsigned int*)l, 16, 0, 0);
}
// one K-half stage step: 2 async16 (row srow and srow + rows/2)
__device__ __forceinline__ void stage2(const short* g, char* d, long rs, int off2) {
    async16(g, d);
    async16(g + rs, d + off2);
}

// ---------------------------------------------------------------------------
// Swizzle (T2, verified round 2: conflicts 4.19M -> 262K):
//   read col-block  qa = (q ^ ((r>>1)&3)) * 8 shorts   (32-short rows)
//   stage col-block sc = ((tid&3) ^ ((tid>>3)&3)) * 8 shorts
// R8: gemm_ln_k A now also uses 32-short rows -> one unified scheme.
// ---------------------------------------------------------------------------

// ---------------------------------------------------------------------------
// bf16 MFMA GEMM 128x128, counted-vmcnt 2-body ledger (round-2 verified;
// 64KB LDS -> 2 blocks/CU).
// ROUND 8: sched_barrier(0) pins REMOVED. The asm "memory" clobbers on the
// vmcnt waits already order all memory ops (ds_read/async16) across body
// boundaries — that is the correctness fence. The pins additionally forced
// every MFMA to drain before the wait/barrier (register-only ops that could
// otherwise overlap into the barrier shadow) — m141's order-pinning cost.
// Waits + barriers byte-identical.
// ---------------------------------------------------------------------------
template<int DO_GELU, int OUT_BF16, int ADD_RES>
__global__ __launch_bounds__(256, 2)
void gemm_mfma_k(const __hip_bfloat16* __restrict__ A,
                 const __hip_bfloat16* __restrict__ WT,
                 const float* __restrict__ bias,
                 const float* __restrict__ R,
                 void* __restrict__ C,
                 int N, int K) {
    __shared__ __align__(16) char smem[65536];
    float* Ep = (float*)smem;

    const int tid  = threadIdx.x;
    const int lane = tid & 63;
    const int wave = tid >> 6;

    const int Lid = blockIdx.y * gridDim.x + blockIdx.x;
    const int xcd = Lid & 7;
    const int idx = Lid >> 3;
    const int gx  = gridDim.x, gy8 = gridDim.y >> 3;
    const int m0 = (xcd * gy8 + idx / gx) * 128;
    const int n0 = (idx % gx) * 128;

    const int wm = (wave >> 1) * 64, wn = (wave & 1) * 64;
    const int r = lane & 15, q = lane >> 4;
    const int qa = (q ^ ((r >> 1) & 3)) * 8;   // T2-fixed de-swizzle

    const int srow = tid >> 2;                 // 0..63
    const int sc = ((tid & 3) ^ ((tid >> 3) & 3)) * 8;
    const short* Ag = (const short*)A + (long)(m0 + srow) * K + sc;
    const short* Bg = (const short*)WT + (long)(n0 + srow) * K + sc;
    const long rs = (long)64 * K;              // +64 rows (shorts)

    floatx4 acc[4][4];
    #pragma unroll
    for (int i = 0; i < 4; i++)
        #pragma unroll
        for (int j = 0; j < 4; j++) acc[i][j] = (floatx4)0.f;

    const int NT = K >> 6;

    stage2(Ag,      smem + 0     + tid * 16, rs, 4096);
    stage2(Bg,      smem + 16384 + tid * 16, rs, 4096);
    stage2(Ag + 32, smem + 8192  + tid * 16, rs, 4096);
    stage2(Bg + 32, smem + 24576 + tid * 16, rs, 4096);
    asm volatile("s_waitcnt vmcnt(4)" ::: "memory");  // ks0 landed
    __builtin_amdgcn_s_barrier();

    short8 a[4], b[4];
    for (int t = 0; t < NT; ++t) {
        const int cur = t & 1, nxt = cur ^ 1;
        const bool hn = (t + 1 < NT);
        const short* As = (const short*)(smem + cur * 32768);
        const short* Bs = (const short*)(smem + cur * 32768 + 16384);
        const short* Agt = Ag + (t + 1) * 64;
        const short* Bgt = Bg + (t + 1) * 64;
        char* Ad = smem + nxt * 32768;
        char* Bd = smem + nxt * 32768 + 16384;

        // ---- body A: ks0 ----
        if (hn) {
            stage2(Agt, Ad + tid * 16, rs, 4096);
            stage2(Bgt, Bd + tid * 16, rs, 4096);
        }
        #pragma unroll
        for (int i = 0; i < 4; i++)
            a[i] = *(const short8*)&As[(wm + i * 16 + r) * 32 + qa];
        #pragma unroll
        for (int j = 0; j < 4; j++)
            b[j] = *(const short8*)&Bs[(wn + j * 16 + r) * 32 + qa];
        #pragma unroll
        for (int i = 0; i < 4; i++)
            #pragma unroll
            for (int j = 0; j < 4; j++)
                acc[i][j] = __builtin_amdgcn_mfma_f32_16x16x32_bf16(
                    a[i], b[j], acc[i][j], 0, 0, 0);
        if (hn) asm volatile("s_waitcnt vmcnt(4)" ::: "memory");
        else    asm volatile("s_waitcnt vmcnt(0)" ::: "memory");
        __builtin_amdgcn_s_barrier();

        // ---- body B: ks1 ----
        if (hn) {
            stage2(Agt + 32, Ad + 8192 + tid * 16, rs, 4096);
            stage2(Bgt + 32, Bd + 8192 + tid * 16, rs, 4096);
        }
        #pragma unroll
        for (int i = 0; i < 4; i++)
            a[i] = *(const short8*)&As[4096 + (wm + i * 16 + r) * 32 + qa];
        #pragma unroll
        for (int j = 0; j < 4; j++)
            b[j] = *(const short8*)&Bs[4096 + (wn + j * 16 + r) * 32 + qa];
        #pragma unroll
        for (int i = 0; i < 4; i++)
            #pragma unroll
            for (int j = 0; j < 4; j++)
                acc[i][j] = __builtin_amdgcn_mfma_f32_16x16x32_bf16(
                    a[i], b[j], acc[i][j], 0, 0, 0);
        if (hn) asm volatile("s_waitcnt vmcnt(4)" ::: "memory");
        __builtin_amdgcn_s_barrier();
    }

    // ---- epilogue: restage through LDS, coalesced postprocess + store ----
    const int erow = tid >> 5;          // 0..7
    const int ecol = (tid & 31) * 4;    // 0..124, float4 granularity
    const float4 bvec = *(const float4*)&bias[n0 + ecol];

    #pragma unroll
    for (int pass = 0; pass < 2; pass++) {
        if (pass) __syncthreads();
        if ((wave >> 1) == pass) {
            #pragma unroll
            for (int i = 0; i < 4; i++)
                #pragma unroll
                for (int j = 0; j < 4; j++)
                    #pragma unroll
                    for (int rg = 0; rg < 4; rg++)
                        Ep[(i * 16 + q * 4 + rg) * 132 + wn + j * 16 + r] =
                            acc[i][j][rg];
        }
        __syncthreads();
        #pragma unroll
        for (int it = 0; it < 8; it++) {
            const int row = it * 8 + erow;
            const long grow = (long)(m0 + pass * 64 + row) * N + n0 + ecol;
            const float4 v = *(const float4*)&Ep[row * 132 + ecol];
            float o0 = v.x + bvec.x, o1 = v.y + bvec.y;
            float o2 = v.z + bvec.z, o3 = v.w + bvec.w;
            if (DO_GELU) {
                o0 = gelu_f(o0); o1 = gelu_f(o1);
                o2 = gelu_f(o2); o3 = gelu_f(o3);
            }
            if (ADD_RES) {
                const float4 rv = *(const float4*)&R[grow];
                o0 += rv.x; o1 += rv.y; o2 += rv.z; o3 += rv.w;
            }
            if (OUT_BF16) {
                ushort4 pk;
                pk.x = f2bf(o0); pk.y = f2bf(o1);
                pk.z = f2bf(o2); pk.w = f2bf(o3);
                *(ushort4*)((unsigned short*)C + grow) = pk;
            } else {
                *(float4*)((float*)C + grow) = make_float4(o0, o1, o2, o3);
            }
        }
    }
}

// ---------------------------------------------------------------------------
// Fused GEMM(+bias+residual)+LayerNorm for N=512 shapes.
// Hout/Hb = LN(A@WT + bias + R)*g+be.  M mult 64, K mult 64 (BK=32 bodies).
// ROUND 8 (v3): occupancy restructure — BK=32, LDS exactly 80KB ->
// 2 blocks/CU (prev 152KB -> 1/CU, zero TLP to hide body dead-time; both
// pipes measured ~20%). Wave layout unchanged (8 waves, 64x64 tile,
// acc[4][4]); A now 32-short rows -> unified verified swizzle.
// LDS: A pair-slots 2x8KB @0/8192 (pair k = tiles 2k,2k+1; half by tid>>8,
// wave-uniform); B bufs 2x32KB @16384/49152.
// FIFO ledger (traced): prologue {B(0):4, Ap(0,1):1} -> vmcnt(0).
//  body t: top issue B(t+1):4 into buf (t+1)&1 (read last body, barrier
//  passed -> no race); even t also issues Ap(t+2,t+3):1 into slot
//  ((t>>1)+1)&1 (read 2 bodies ago). reads tile t; 16 MFMA;
//  wait even->vmcnt(1) [retires B(t+1)], odd->vmcnt(0) [retires Ap+B];
//  barrier. A exposure >= 1 full body; B exposure = this body's compute
//  (L2-resident weights) + 2nd-block TLP. Tail index-clamped (redundant
//  loads land in slots/bufs never read again); post-loop vmcnt(0)+barrier
//  drains before smem reuse as Ef.
// Epilogue: 2 chunks x 32 rows (R5-verified form), Ef[32][516]=66KB.
// No sched_barrier pins (asm "memory" orders all memory ops; MFMAs free
// to overlap the barrier shadow). In-place R==Hout safe (own 64 rows only).
// ---------------------------------------------------------------------------
__global__ __launch_bounds__(512, 4)
void gemm_ln_k(const __hip_bfloat16* __restrict__ A,
               const __hip_bfloat16* __restrict__ WT,
               const float* __restrict__ bias,
               const float* R,                    // no restrict: aliases Hout
               const float* __restrict__ g,
               const float* __restrict__ be,
               float* Hout,                       // no restrict: aliases R
               __hip_bfloat16* __restrict__ Hb,
               int K) {
    __shared__ __align__(16) char smem[81920];
    const int tid  = threadIdx.x;
    const int lane = tid & 63;
    const int wave = tid >> 6;

    // XCD swizzle (grid = 256 = 32 per XCD, bijective)
    const int Lid = blockIdx.x;
    const int m0 = ((Lid & 7) * 32 + (Lid >> 3)) * 64;

    const int r = lane & 15, q = lane >> 4;
    const int qa = (q ^ ((r >> 1) & 3)) * 8;  // unified 32-short-row swizzle
    const int wn = wave * 64;                 // wave's 64-column slab

    // B staging: 4 loads/thread/tile; rows tid>>2 + j*128
    const int brow = tid >> 2;
    const int bsb  = ((tid & 3) ^ ((tid >> 3) & 3)) * 8;
    const short* Bg = (const short*)WT + (long)brow * K + bsb;
    const long brs = (long)128 * K;

    // A pair staging: 1 load/thread per 2 tiles; half = tid>>8 (wave-uniform)
    const int ahalf  = tid >> 8;
    const int alocal = tid & 255;
    const int arow   = alocal >> 2;           // 0..63
    const int asb    = ((alocal & 3) ^ ((alocal >> 3) & 3)) * 8;
    const short* Ag  = (const short*)A + (long)(m0 + arow) * K + asb;

    floatx4 acc[4][4];
    #pragma unroll
    for (int i = 0; i < 4; i++)
        #pragma unroll
        for (int j = 0; j < 4; j++) acc[i][j] = (floatx4)0.f;

    const int NTT = K >> 5;   // BK=32 bodies

    // prologue: B(0):4 -> buf0 ; Ap(0,1):1 -> slot0
    {
        char* d0 = smem + 16384 + tid * 16;
        async16(Bg, d0); async16(Bg + brs, d0 + 8192);
        async16(Bg + 2 * brs, d0 + 16384); async16(Bg + 3 * brs, d0 + 24576);
        const int ka = (ahalf < NTT) ? ahalf : NTT - 1;
        async16(Ag + (long)ka * 32, smem + tid * 16);
    }
    asm volatile("s_waitcnt vmcnt(0)" ::: "memory");
    __builtin_amdgcn_s_barrier();

    for (int t = 0; t < NTT; ++t) {
        // top: issue B(t+1) into buf (t+1)&1 (fully read last body)
        {
            const int kb = (t + 1 < NTT) ? t + 1 : NTT - 1;
            const short* p = Bg + (long)kb * 32;
            char* d = smem + 16384 + ((t + 1) & 1) * 32768 + tid * 16;
            async16(p, d); async16(p + brs, d + 8192);
            async16(p + 2 * brs, d + 16384); async16(p + 3 * brs, d + 24576);
        }
        if (!(t & 1)) {  // even: issue Apair(t+2,t+3) into the other slot
            const int kt = t + 2 + ahalf;
            const int ka = (kt < NTT) ? kt : NTT - 1;
            async16(Ag + (long)ka * 32,
                    smem + (((t >> 1) + 1) & 1) * 8192 + tid * 16);
        }
        // reads of tile t
        const short* As = (const short*)(smem + ((t >> 1) & 1) * 8192 +
                                         (t & 1) * 4096);
        const short* Bs = (const short*)(smem + 16384 + (t & 1) * 32768);
        short8 a[4], b[4];
        #pragma unroll
        for (int mf = 0; mf < 4; mf++)
            a[mf] = *(const short8*)&As[(mf * 16 + r) * 32 + qa];
        #pragma unroll
        for (int nf = 0; nf < 4; nf++)
            b[nf] = *(const short8*)&Bs[(wn + nf * 16 + r) * 32 + qa];
        #pragma unroll
        for (int mf = 0; mf < 4; mf++)
            #pragma unroll
            for (int nf = 0; nf < 4; nf++)
                acc[mf][nf] = __builtin_amdgcn_mfma_f32_16x16x32_bf16(
                    a[mf], b[nf], acc[mf][nf], 0, 0, 0);
        if (!(t & 1)) asm volatile("s_waitcnt vmcnt(1)" ::: "memory");
        else          asm volatile("s_waitcnt vmcnt(0)" ::: "memory");
        __builtin_amdgcn_s_barrier();
    }

    // drain clamped tail loads before smem reuse as Ef
    asm volatile("s_waitcnt vmcnt(0)" ::: "memory");
    __builtin_amdgcn_s_barrier();

    // ---- fused epilogue: 2 chunks of 32 rows ----
    float* Ef = (float*)smem;                  // [32][516] = 66048 B
    float* stat = (float*)(smem + 66048);
    const float gl = g[tid], bl = be[tid], bv = bias[tid];

    #pragma unroll
    for (int ch = 0; ch < 2; ch++) {
        if (ch) __syncthreads();               // ch0 readers done before reuse
        #pragma unroll
        for (int m2 = 0; m2 < 2; m2++)
            #pragma unroll
            for (int nf = 0; nf < 4; nf++)
                #pragma unroll
                for (int rg = 0; rg < 4; rg++)
                    Ef[(m2 * 16 + q * 4 + rg) * 516 + wn + nf * 16 + r] =
                        acc[2 * ch + m2][nf][rg];
        __syncthreads();
        const int gm = m0 + ch * 32;
        // bias + residual, coalesced (thread t owns column t of 32 rows)
        #pragma unroll 8
        for (int k = 0; k < 32; k++)
            Ef[k * 516 + tid] += bv + R[(long)(gm + k) * 512 + tid];
        __syncthreads();
        // per-row stats: 16 threads per row, 32 cols each
        {
            const int row = tid >> 4, cc = tid & 15;
            float s = 0.f, ss = 0.f;
            #pragma unroll 8
            for (int j = 0; j < 32; j++) {
                const float v = Ef[row * 516 + cc + 16 * j];
                s += v; ss += v * v;
            }
            #pragma unroll
            for (int off = 1; off < 16; off <<= 1) {
                s  += __shfl_xor(s, off);
                ss += __shfl_xor(ss, off);
            }
            const float mu  = s * (1.0f / 512.0f);
            const float var = fmaxf(ss * (1.0f / 512.0f) - mu * mu, 0.f);
            const float inv = 1.0f / sqrtf(var + 1e-5f);
            if (cc == 0) { stat[row * 2] = mu; stat[row * 2 + 1] = inv; }
        }
        __syncthreads();
        // normalize + store, coalesced
        #pragma unroll 8
        for (int k = 0; k < 32; k++) {
            const float v  = Ef[k * 516 + tid];
            const float o  = (v - stat[k * 2]) * stat[k * 2 + 1] * gl + bl;
            const long idx = (long)(gm + k) * 512 + tid;
            Hout[idx] = o;
            ((unsigned short*)Hb)[idx] = f2bf(o);
        }
    }
}

// ---------------------------------------------------------------------------
// WT[l][n][k] = (bf16) W[l][k][n]
// ---------------------------------------------------------------------------
__global__ __launch_bounds__(256)
void transpose_cast_k(const float* __restrict__ W, __hip_bfloat16* __restrict__ WT,
                      int K, int N) {
    __shared__ float tile[32][33];
    const float* Wl = W + (long)blockIdx.z * K * N;
    __hip_bfloat16* WTl = WT + (long)blockIdx.z * K * N;
    const int n0 = blockIdx.x * 32, k0 = blockIdx.y * 32;
    const int tx = threadIdx.x & 31, ty = threadIdx.x >> 5;
    for (int rr = ty; rr < 32; rr += 8)
        tile[rr][tx] = Wl[(long)(k0 + rr) * N + n0 + tx];
    __syncthreads();
    for (int rr = ty; rr < 32; rr += 8)
        WTl[(long)(n0 + rr) * K + k0 + tx] = __float2bfloat16(tile[tx][rr]);
}

// ---------------------------------------------------------------------------
// fp32 tiled GEMM (in-proj only: M=16384, N=512, K=32)
// ---------------------------------------------------------------------------
template<int DO_GELU>
__global__ __launch_bounds__(256)
void gemm_bias_k(const float* __restrict__ A, long lda,
                 const float* __restrict__ W,
                 const float* __restrict__ bias,
                 float* __restrict__ C,
                 int M, int N, int K) {
    __shared__ float As[16][64];
    __shared__ float Ws[16][64];
    const int tx = threadIdx.x;
    const int ty = threadIdx.y;
    const int tid = ty * 16 + tx;
    const int m0 = blockIdx.y * 64;
    const int n0 = blockIdx.x * 64;
    float acc[4][4] = {};
    for (int k0 = 0; k0 < K; k0 += 16) {
        #pragma unroll
        for (int e = tid; e < 64 * 16; e += 256) {
            int m = e >> 4, k = e & 15;
            float v = 0.f;
            if (m0 + m < M) v = A[(long)(m0 + m) * lda + k0 + k];
            As[k][m] = v;
        }
        #pragma unroll
        for (int e = tid; e < 16 * 64; e += 256) {
            int k = e >> 6, n = e & 63;
            float v = 0.f;
            if (n0 + n < N) v = W[(long)(k0 + k) * N + n0 + n];
            Ws[k][n] = v;
        }
        __syncthreads();
        #pragma unroll
        for (int kk = 0; kk < 16; kk++) {
            float a[4], w[4];
            #pragma unroll
            for (int i = 0; i < 4; i++) a[i] = As[kk][ty * 4 + i];
            #pragma unroll
            for (int j = 0; j < 4; j++) w[j] = Ws[kk][tx * 4 + j];
            #pragma unroll
            for (int i = 0; i < 4; i++)
                #pragma unroll
                for (int j = 0; j < 4; j++)
                    acc[i][j] += a[i] * w[j];
        }
        __syncthreads();
    }
    #pragma unroll
    for (int i = 0; i < 4; i++) {
        int m = m0 + ty * 4 + i;
        if (m >= M) continue;
        #pragma unroll
        for (int j = 0; j < 4; j++) {
            int n = n0 + tx * 4 + j;
            if (n >= N) continue;
            float v = acc[i][j] + bias[n];
            if (DO_GELU) v = gelu_f(v);
            C[(long)m * N + n] = v;
        }
    }
}

// ---------------------------------------------------------------------------
// h = gelu(layernorm(X)) + pe ; also bf16 copy hb  (runs once)
// ---------------------------------------------------------------------------
__global__ __launch_bounds__(256)
void ln_gelu_pos_k(const float* __restrict__ X,
                   const float* __restrict__ g,
                   const float* __restrict__ be,
                   float* __restrict__ Hout,
                   __hip_bfloat16* __restrict__ Hb) {
    const int row = blockIdx.x;
    const int s = row & (S_ - 1);
    const int t = threadIdx.x;
    const float* x = X + (long)row * D_;
    float v0 = x[t], v1 = x[t + 256];
    __shared__ float red[256];
    red[t] = v0 + v1;
    __syncthreads();
    for (int off = 128; off; off >>= 1) {
        if (t < off) red[t] += red[t + off];
        __syncthreads();
    }
    float mu = red[0] * (1.0f / D_);
    __syncthreads();
    float d0 = v0 - mu, d1 = v1 - mu;
    red[t] = d0 * d0 + d1 * d1;
    __syncthreads();
    for (int off = 128; off; off >>= 1) {
        if (t < off) red[t] += red[t + off];
        __syncthreads();
    }
    float var = red[0] * (1.0f / D_);
    float inv = 1.0f / sqrtf(var + 1e-5f);
    float o0 = gelu_f(d0 * inv * g[t] + be[t]);
    float o1 = gelu_f(d1 * inv * g[t + 256] + be[t + 256]);
    {
        int d = t, i = d >> 1;
        float dv = expf((float)(2 * i) * (-9.210340371976184f / 512.0f));
        float ang = (float)s * dv;
        o0 += (d & 1) ? cosf(ang) : sinf(ang);
    }
    {
        int d = t + 256, i = d >> 1;
        float dv = expf((float)(2 * i) * (-9.210340371976184f / 512.0f));
        float ang = (float)s * dv;
        o1 += (d & 1) ? cosf(ang) : sinf(ang);
    }
    Hout[(long)row * D_ + t] = o0;
    Hout[(long)row * D_ + t + 256] = o1;
    Hb[(long)row * D_ + t] = __float2bfloat16(o0);
    Hb[(long)row * D_ + t + 256] = __float2bfloat16(o1);
}

// ---------------------------------------------------------------------------
// MFMA flash attention (verified structure, unchanged)
// ---------------------------------------------------------------------------
#define LDT 72
__global__ __launch_bounds__(256)
void attn_mfma_k(const __hip_bfloat16* __restrict__ qkv,
                 __hip_bfloat16* __restrict__ O) {
    const int qt = blockIdx.x;
    const int bh = blockIdx.y;
    const int b = bh >> 3, h = bh & (H_ - 1);
    const int tid = threadIdx.x;
    const int wave = tid >> 6, lane = tid & 63;
    const int ln = lane & 15, quad = lane >> 4;
    const int wm = wave * 32;
    const int i0 = qt * 128;

    __shared__ unsigned short Qs[128 * LDT];
    __shared__ unsigned short Ks[64 * LDT];
    __shared__ unsigned short Vt[64 * LDT];
    __shared__ unsigned short Ps[128 * LDT];
    __shared__ float stat[128];

    const unsigned short* base = (const unsigned short*)qkv + (long)b * S_ * (3 * D_);

    {
        const int r0 = tid >> 3, c0 = (tid & 7) * 8;
        #pragma unroll
        for (int i = 0; i < 4; i++) {
            const int rw = i * 32 + r0;
            *(short8*)&Qs[rw * LDT + c0] =
                *(const short8*)(base + (long)(i0 + rw) * (3 * D_) + h * HD_ + c0);
        }
    }

    float m_i[2] = { -INFINITY, -INFINITY };
    float l_i[2] = { 0.f, 0.f };
    floatx4 o_acc[2][4];
    #pragma unroll
    for (int i = 0; i < 2; i++)
        #pragma unroll
        for (int j = 0; j < 4; j++) o_acc[i][j] = (floatx4)0.f;

    const int kr = tid >> 2, kc = (tid & 3) * 16;
    const int vj = tid & 63, vc = (tid >> 6) * 16;

    const int ktmax = 2 * qt + 1;
    for (int kt = 0; kt <= ktmax; kt++) {
        const int j0 = kt * 64;
        {
            const unsigned short* kp = base + (long)(j0 + kr) * (3 * D_) + D_ + h * HD_ + kc;
            *(short8*)&Ks[kr * LDT + kc]     = *(const short8*)(kp);
            *(short8*)&Ks[kr * LDT + kc + 8] = *(const short8*)(kp + 8);
            const unsigned short* vp = base + (long)(j0 + vj) * (3 * D_) + 2 * D_ + h * HD_ + vc;
            short8 v0 = *(const short8*)(vp);
            short8 v1 = *(const short8*)(vp + 8);
            #pragma unroll
            for (int e = 0; e < 8; e++) {
                Vt[(vc + e) * LDT + vj]     = (unsigned short)v0[e];
                Vt[(vc + 8 + e) * LDT + vj] = (unsigned short)v1[e];
            }
        }
        __syncthreads();

        floatx4 sa[4][2];
        #pragma unroll
        for (int mt = 0; mt < 4; mt++)
            #pragma unroll
            for (int nt = 0; nt < 2; nt++) sa[mt][nt] = (floatx4)0.f;
        #pragma unroll
        for (int c = 0; c < 2; c++) {
            short8 kf[4], qf[2];
            #pragma unroll
            for (int mt = 0; mt < 4; mt++)
                kf[mt] = *(const short8*)&Ks[(mt * 16 + ln) * LDT + c * 32 + quad * 8];
            #pragma unroll
            for (int nt = 0; nt < 2; nt++)
                qf[nt] = *(const short8*)&Qs[(wm + nt * 16 + ln) * LDT + c * 32 + quad * 8];
            #pragma unroll
            for (int mt = 0; mt < 4; mt++)
                #pragma unroll
                for (int nt = 0; nt < 2; nt++)
                    sa[mt][nt] = __builtin_amdgcn_mfma_f32_16x16x32_bf16(
                        kf[mt], qf[nt], sa[mt][nt], 0, 0, 0);
        }

        const bool domask = (kt >= 2 * qt);
        #pragma unroll
        for (int nt = 0; nt < 2; nt++) {
            const int qg = i0 + wm + nt * 16 + ln;
            float mx = -INFINITY;
            #pragma unroll
            for (int mt = 0; mt < 4; mt++)
                #pragma unroll
                for (int rg = 0; rg < 4; rg++) {
                    float v = sa[mt][nt][rg] * 0.125f;
                    if (domask && (j0 + mt * 16 + quad * 4 + rg > qg)) v = -INFINITY;
                    sa[mt][nt][rg] = v;
                    mx = fmaxf(mx, v);
                }
            mx = fmaxf(mx, __shfl_xor(mx, 16));
            mx = fmaxf(mx, __shfl_xor(mx, 32));
            const float mn = fmaxf(m_i[nt], mx);
            const float alpha = __expf(m_i[nt] - mn);
            m_i[nt] = mn;
            float ls = 0.f;
            #pragma unroll
            for (int mt = 0; mt < 4; mt++) {
                ushort4 pk;
                float p0 = __expf(sa[mt][nt][0] - mn);
                float p1 = __expf(sa[mt][nt][1] - mn);
                float p2 = __expf(sa[mt][nt][2] - mn);
                float p3 = __expf(sa[mt][nt][3] - mn);
                ls += p0 + p1 + p2 + p3;
                pk.x = f2bf(p0); pk.y = f2bf(p1); pk.z = f2bf(p2); pk.w = f2bf(p3);
                *(ushort4*)&Ps[(wm + nt * 16 + ln) * LDT + mt * 16 + quad * 4] = pk;
            }
            ls += __shfl_xor(ls, 16);
            ls += __shfl_xor(ls, 32);
            l_i[nt] = l_i[nt] * alpha + ls;
            if (quad == 0) stat[wm + nt * 16 + ln] = alpha;
        }

        #pragma unroll
        for (int mt2 = 0; mt2 < 2; mt2++) {
            #pragma unroll
            for (int rg = 0; rg < 4; rg++) {
                const float a = stat[wm + mt2 * 16 + quad * 4 + rg];
                #pragma unroll
                for (int nt = 0; nt < 4; nt++) o_acc[mt2][nt][rg] *= a;
            }
        }

        #pragma unroll
        for (int c = 0; c < 2; c++) {
            short8 pf[2], vf[4];
            #pragma unroll
            for (int mt2 = 0; mt2 < 2; mt2++)
                pf[mt2] = *(const short8*)&Ps[(wm + mt2 * 16 + ln) * LDT + c * 32 + quad * 8];
            #pragma unroll
            for (int nt = 0; nt < 4; nt++)
                vf[nt] = *(const short8*)&Vt[(nt * 16 + ln) * LDT + c * 32 + quad * 8];
            #pragma unroll
            for (int mt2 = 0; mt2 < 2; mt2++)
                #pragma unroll
                for (int nt = 0; nt < 4; nt++)
                    o_acc[mt2][nt] = __builtin_amdgcn_mfma_f32_16x16x32_bf16(
                        pf[mt2], vf[nt], o_acc[mt2][nt], 0, 0, 0);
        }
        __syncthreads();
    }

    if (quad == 0) {
        stat[wm + ln]      = l_i[0];
        stat[wm + 16 + ln] = l_i[1];
    }
    unsigned short* Og = (unsigned short*)O;
    #pragma unroll
    for (int mt2 = 0; mt2 < 2; mt2++) {
        #pragma unroll
        for (int rg = 0; rg < 4; rg++) {
            const float linv = 1.0f / stat[wm + mt2 * 16 + quad * 4 + rg];
            const long row = (long)(b * S_ + i0 + wm + mt2 * 16 + quad * 4 + rg);
            #pragma unroll
            for (int nt = 0; nt < 4; nt++)
                Og[row * D_ + h * HD_ + nt * 16 + ln] =
                    f2bf(o_acc[mt2][nt][rg] * linv);
        }
    }
}

// ---------------------------------------------------------------------------
// Head kernels
// ---------------------------------------------------------------------------
__global__ __launch_bounds__(256)
void head1_k(const float* __restrict__ h, const float* __restrict__ w1,
             const float* __restrict__ b1, float* __restrict__ th) {
    __shared__ float hs[D_];
    const int b = blockIdx.x, n = threadIdx.x;
    const float* hr = h + (long)(b * S_ + S_ - 1) * D_;
    hs[n] = hr[n];
    hs[n + 256] = hr[n + 256];
    __syncthreads();
    float s = 0.f;
    #pragma unroll 8
    for (int k = 0; k < D_; k++) s += hs[k] * w1[(long)k * 256 + n];
    th[b * 256 + n] = gelu_f(s + b1[n]);
}

__global__ __launch_bounds__(64)
void head2_k(const float* __restrict__ th, const float* __restrict__ w2,
             const float* __restrict__ b2, float* __restrict__ out) {
    const int b = blockIdx.x, lane = threadIdx.x;
    const float* t = th + b * 256;
    float s0 = 0.f, s1 = 0.f, s2 = 0.f;
    #pragma unroll
    for (int e = 0; e < 4; e++) {
        const int k = lane * 4 + e;
        const float tv = t[k];
        s0 += tv * w2[k * 3 + 0];
        s1 += tv * w2[k * 3 + 1];
        s2 += tv * w2[k * 3 + 2];
    }
    #pragma unroll
    for (int off = 1; off < 64; off <<= 1) {
        s0 += __shfl_xor(s0, off);
        s1 += __shfl_xor(s1, off);
        s2 += __shfl_xor(s2, off);
    }
    if (lane == 0) {
        out[b * 3 + 0] = s0 + b2[0];
        out[b * 3 + 1] = s1 + b2[1];
        out[b * 3 + 2] = s2 + b2[2];
    }
}

// ---------------------------------------------------------------------------
extern "C" void kernel_launch(void* const* d_in, const int* in_sizes, int n_in,
                              void* d_out, int out_size, void* d_ws, size_t ws_size,
                              hipStream_t stream) {
    const float* x     = (const float*)d_in[0];
    const float* w_in  = (const float*)d_in[1];
    const float* b_in  = (const float*)d_in[2];
    const float* g_in  = (const float*)d_in[3];
    const float* be_in = (const float*)d_in[4];
    const float* w_qkv = (const float*)d_in[5];
    const float* b_qkv = (const float*)d_in[6];
    const float* w_out = (const float*)d_in[7];
    const float* b_out = (const float*)d_in[8];
    const float* g1    = (const float*)d_in[9];
    const float* be1   = (const float*)d_in[10];
    const float* w_ff1 = (const float*)d_in[11];
    const float* b_ff1 = (const float*)d_in[12];
    const float* w_ff2 = (const float*)d_in[13];
    const float* b_ff2 = (const float*)d_in[14];
    const float* g2    = (const float*)d_in[15];
    const float* be2   = (const float*)d_in[16];
    const float* w_h1  = (const float*)d_in[17];
    const float* b_h1  = (const float*)d_in[18];
    const float* w_h2  = (const float*)d_in[19];
    const float* b_h2  = (const float*)d_in[20];
    float* out = (float*)d_out;

    float* h    = (float*)d_ws;
    float* bufB = h + (long)M_ * D_;
    float* th   = bufB + (long)M_ * D_;
    __hip_bfloat16* hb    = (__hip_bfloat16*)(th + 32 * 256);
    __hip_bfloat16* attb  = hb + (long)M_ * D_;
    __hip_bfloat16* bufAb = attb + (long)M_ * D_;
    __hip_bfloat16* qkvT  = bufAb + (long)M_ * FF_;
    __hip_bfloat16* outT  = qkvT + (long)L_ * (3 * D_) * D_;
    __hip_bfloat16* ff1T  = outT + (long)L_ * D_ * D_;
    __hip_bfloat16* ff2T  = ff1T + (long)L_ * FF_ * D_;

    dim3 blk(16, 16);

    transpose_cast_k<<<dim3((3 * D_) / 32, D_ / 32, L_), 256, 0, stream>>>(w_qkv, qkvT, D_, 3 * D_);
    transpose_cast_k<<<dim3(D_ / 32, D_ / 32, L_), 256, 0, stream>>>(w_out, outT, D_, D_);
    transpose_cast_k<<<dim3(FF_ / 32, D_ / 32, L_), 256, 0, stream>>>(w_ff1, ff1T, D_, FF_);
    transpose_cast_k<<<dim3(D_ / 32, FF_ / 32, L_), 256, 0, stream>>>(w_ff2, ff2T, FF_, D_);

    gemm_bias_k<0><<<dim3(D_ / 64, M_ / 64), blk, 0, stream>>>(
        x, IN_, w_in, b_in, bufB, M_, D_, IN_);
    ln_gelu_pos_k<<<M_, 256, 0, stream>>>(bufB, g_in, be_in, h, hb);

    for (int l = 0; l < L_; l++) {
        // qkv -> bf16 bufAb (128^2 counted-vmcnt, 1536 blocks)
        gemm_mfma_k<0, 1, 0><<<dim3((3 * D_) / 128, M_ / 128), 256, 0, stream>>>(
            hb, qkvT + (long)l * (3 * D_) * D_, b_qkv + l * 3 * D_, nullptr,
            bufAb, 3 * D_, D_);
        attn_mfma_k<<<dim3(S_ / 128, B_ * H_), 256, 0, stream>>>(bufAb, attb);
        // fused: h = LN(attb @ outT + b_out + h)  (writes h fp32 + hb bf16)
        gemm_ln_k<<<256, 512, 0, stream>>>(
            attb, outT + (long)l * D_ * D_, b_out + l * D_, h,
            g1 + l * D_, be1 + l * D_, h, hb, D_);
        // ff1 -> bf16 bufAb (gelu)  (128^2 counted-vmcnt, 2048 blocks, 2/CU)
        gemm_mfma_k<1, 1, 0><<<dim3(FF_ / 128, M_ / 128), 256, 0, stream>>>(
            hb, ff1T + (long)l * FF_ * D_, b_ff1 + l * FF_, nullptr,
            bufAb, FF_, D_);
        // fused: h = LN(bufAb @ ff2T + b_ff2 + h)
        gemm_ln_k<<<256, 512, 0, stream>>>(
            bufAb, ff2T + (long)l * D_ * FF_, b_ff2 + l * D_, h,
            g2 + l * D_, be2 + l * D_, h, hb, FF_);
    }

    head1_k<<<B_, 256, 0, stream>>>(h, w_h1, b_h1, th);
    head2_k<<<B_, 64, 0, stream>>>(th, w_h2, b_h2, out);
}

// Round 9
// 1594.744 us; speedup vs baseline: 1.0765x; 1.0765x over previous
//
#include <hip/hip_runtime.h>
#include <hip/hip_bf16.h>
#include <math.h>

#define D_   512
#define H_   8
#define HD_  64
#define L_   6
#define FF_  2048
#define IN_  32
#define OUT_ 3
#define S_   512
#define B_   32
#define M_   (B_ * S_)   // 16384 token rows

typedef __attribute__((ext_vector_type(8))) short short8;
typedef __attribute__((ext_vector_type(4))) float floatx4;

// Branchless gelu: 0.5x(1+erf(x/sqrt2)), erf via A&S 7.1.26 (max err 1.5e-7).
__device__ __forceinline__ float gelu_f(float x) {
    const float ax = fabsf(x) * 0.70710678118654752f;
    const float t = __builtin_amdgcn_rcpf(fmaf(0.3275911f, ax, 1.0f));
    float p = fmaf(1.061405429f, t, -1.453152027f);
    p = fmaf(p, t, 1.421413741f);
    p = fmaf(p, t, -0.284496736f);
    p = fmaf(p, t, 0.254829592f);
    p = p * t;
    const float e = __expf(-ax * ax);
    const float er = copysignf(fmaf(-p, e, 1.0f), x);
    return 0.5f * x * (1.0f + er);
}
__device__ __forceinline__ float bf2f(unsigned short u) {
    union { unsigned int i; float f; } c; c.i = ((unsigned)u) << 16; return c.f;
}
__device__ __forceinline__ unsigned short f2bf(float v) {
    __hip_bfloat16 t = __float2bfloat16(v);
    return *(unsigned short*)&t;
}
__device__ __forceinline__ void async16(const void* g, void* l) {
    __builtin_amdgcn_global_load_lds(
        (const __attribute__((address_space(1))) unsigned int*)g,
        (__attribute__((address_space(3))) unsigned int*)l, 16, 0, 0);
}
// one K-half stage step: 2 async16 (row srow and srow + rows/2)
__device__ __forceinline__ void stage2(const short* g, char* d, long rs, int off2) {
    async16(g, d);
    async16(g + rs, d + off2);
}

// ---------------------------------------------------------------------------
// Swizzle (T2, verified round 2: conflicts 4.19M -> 262K):
//   read col-block  qa = (q ^ ((r>>1)&3)) * 8 shorts   (32-short rows)
//   stage col-block sc = ((tid&3) ^ ((tid>>3)&3)) * 8 shorts
// 64-short rows (gemm_ln_k A): qa = ((ks*4+q) ^ (r&7))*8, src (t&7)^((t>>3)&7)
// ---------------------------------------------------------------------------

// ---------------------------------------------------------------------------
// bf16 MFMA GEMM 128x128, counted-vmcnt 2-body ledger (round-2 verified;
// 64KB LDS -> 2 blocks/CU). R8 pin removal kept (measured neutral: R7->R8
// total delta fully accounted by gemm_ln regression; pins only forced MFMA
// drain before barriers). Waits + barriers unchanged since R2.
// ---------------------------------------------------------------------------
template<int DO_GELU, int OUT_BF16, int ADD_RES>
__global__ __launch_bounds__(256, 2)
void gemm_mfma_k(const __hip_bfloat16* __restrict__ A,
                 const __hip_bfloat16* __restrict__ WT,
                 const float* __restrict__ bias,
                 const float* __restrict__ R,
                 void* __restrict__ C,
                 int N, int K) {
    __shared__ __align__(16) char smem[65536];
    float* Ep = (float*)smem;

    const int tid  = threadIdx.x;
    const int lane = tid & 63;
    const int wave = tid >> 6;

    const int Lid = blockIdx.y * gridDim.x + blockIdx.x;
    const int xcd = Lid & 7;
    const int idx = Lid >> 3;
    const int gx  = gridDim.x, gy8 = gridDim.y >> 3;
    const int m0 = (xcd * gy8 + idx / gx) * 128;
    const int n0 = (idx % gx) * 128;

    const int wm = (wave >> 1) * 64, wn = (wave & 1) * 64;
    const int r = lane & 15, q = lane >> 4;
    const int qa = (q ^ ((r >> 1) & 3)) * 8;   // T2-fixed de-swizzle

    const int srow = tid >> 2;                 // 0..63
    const int sc = ((tid & 3) ^ ((tid >> 3) & 3)) * 8;
    const short* Ag = (const short*)A + (long)(m0 + srow) * K + sc;
    const short* Bg = (const short*)WT + (long)(n0 + srow) * K + sc;
    const long rs = (long)64 * K;              // +64 rows (shorts)

    floatx4 acc[4][4];
    #pragma unroll
    for (int i = 0; i < 4; i++)
        #pragma unroll
        for (int j = 0; j < 4; j++) acc[i][j] = (floatx4)0.f;

    const int NT = K >> 6;

    stage2(Ag,      smem + 0     + tid * 16, rs, 4096);
    stage2(Bg,      smem + 16384 + tid * 16, rs, 4096);
    stage2(Ag + 32, smem + 8192  + tid * 16, rs, 4096);
    stage2(Bg + 32, smem + 24576 + tid * 16, rs, 4096);
    asm volatile("s_waitcnt vmcnt(4)" ::: "memory");  // ks0 landed
    __builtin_amdgcn_s_barrier();

    short8 a[4], b[4];
    for (int t = 0; t < NT; ++t) {
        const int cur = t & 1, nxt = cur ^ 1;
        const bool hn = (t + 1 < NT);
        const short* As = (const short*)(smem + cur * 32768);
        const short* Bs = (const short*)(smem + cur * 32768 + 16384);
        const short* Agt = Ag + (t + 1) * 64;
        const short* Bgt = Bg + (t + 1) * 64;
        char* Ad = smem + nxt * 32768;
        char* Bd = smem + nxt * 32768 + 16384;

        // ---- body A: ks0 ----
        if (hn) {
            stage2(Agt, Ad + tid * 16, rs, 4096);
            stage2(Bgt, Bd + tid * 16, rs, 4096);
        }
        #pragma unroll
        for (int i = 0; i < 4; i++)
            a[i] = *(const short8*)&As[(wm + i * 16 + r) * 32 + qa];
        #pragma unroll
        for (int j = 0; j < 4; j++)
            b[j] = *(const short8*)&Bs[(wn + j * 16 + r) * 32 + qa];
        #pragma unroll
        for (int i = 0; i < 4; i++)
            #pragma unroll
            for (int j = 0; j < 4; j++)
                acc[i][j] = __builtin_amdgcn_mfma_f32_16x16x32_bf16(
                    a[i], b[j], acc[i][j], 0, 0, 0);
        if (hn) asm volatile("s_waitcnt vmcnt(4)" ::: "memory");
        else    asm volatile("s_waitcnt vmcnt(0)" ::: "memory");
        __builtin_amdgcn_s_barrier();

        // ---- body B: ks1 ----
        if (hn) {
            stage2(Agt + 32, Ad + 8192 + tid * 16, rs, 4096);
            stage2(Bgt + 32, Bd + 8192 + tid * 16, rs, 4096);
        }
        #pragma unroll
        for (int i = 0; i < 4; i++)
            a[i] = *(const short8*)&As[4096 + (wm + i * 16 + r) * 32 + qa];
        #pragma unroll
        for (int j = 0; j < 4; j++)
            b[j] = *(const short8*)&Bs[4096 + (wn + j * 16 + r) * 32 + qa];
        #pragma unroll
        for (int i = 0; i < 4; i++)
            #pragma unroll
            for (int j = 0; j < 4; j++)
                acc[i][j] = __builtin_amdgcn_mfma_f32_16x16x32_bf16(
                    a[i], b[j], acc[i][j], 0, 0, 0);
        if (hn) asm volatile("s_waitcnt vmcnt(4)" ::: "memory");
        __builtin_amdgcn_s_barrier();
    }

    // ---- epilogue: restage through LDS, coalesced postprocess + store ----
    const int erow = tid >> 5;          // 0..7
    const int ecol = (tid & 31) * 4;    // 0..124, float4 granularity
    const float4 bvec = *(const float4*)&bias[n0 + ecol];

    #pragma unroll
    for (int pass = 0; pass < 2; pass++) {
        if (pass) __syncthreads();
        if ((wave >> 1) == pass) {
            #pragma unroll
            for (int i = 0; i < 4; i++)
                #pragma unroll
                for (int j = 0; j < 4; j++)
                    #pragma unroll
                    for (int rg = 0; rg < 4; rg++)
                        Ep[(i * 16 + q * 4 + rg) * 132 + wn + j * 16 + r] =
                            acc[i][j][rg];
        }
        __syncthreads();
        #pragma unroll
        for (int it = 0; it < 8; it++) {
            const int row = it * 8 + erow;
            const long grow = (long)(m0 + pass * 64 + row) * N + n0 + ecol;
            const float4 v = *(const float4*)&Ep[row * 132 + ecol];
            float o0 = v.x + bvec.x, o1 = v.y + bvec.y;
            float o2 = v.z + bvec.z, o3 = v.w + bvec.w;
            if (DO_GELU) {
                o0 = gelu_f(o0); o1 = gelu_f(o1);
                o2 = gelu_f(o2); o3 = gelu_f(o3);
            }
            if (ADD_RES) {
                const float4 rv = *(const float4*)&R[grow];
                o0 += rv.x; o1 += rv.y; o2 += rv.z; o3 += rv.w;
            }
            if (OUT_BF16) {
                ushort4 pk;
                pk.x = f2bf(o0); pk.y = f2bf(o1);
                pk.z = f2bf(o2); pk.w = f2bf(o3);
                *(ushort4*)((unsigned short*)C + grow) = pk;
            } else {
                *(float4*)((float*)C + grow) = make_float4(o0, o1, o2, o3);
            }
        }
    }
}

// ---------------------------------------------------------------------------
// Fused GEMM(+bias+residual)+LayerNorm for N=512 shapes.
// ROUND 9: VERBATIM REVERT to the R7-measured config (62.8us ff2).
// R8's 80KB/BK=32 "2 blocks/CU" premise was wrong — grid=256 is exactly
// 1 block/CU, so no TLP materialized while the body count doubled (81us).
// R7 config: BK=64, A triple-slot distance-2, 152KB LDS, vmcnt(5) ledger:
//   prologue [Bks0(0):4, A(0):1, A(1):1, Bks1(0):4] -> vmcnt(5)
//   bodyA(t): issue Bks0(t+1):4, A(t+2):1 -> MFMA ks0 -> vmcnt(5)
//     [retires A(t+1) (2 bodies old) + Bks1(t) (1 body old)]
//   bodyB(t): issue Bks1(t+1):4 -> MFMA ks1 -> vmcnt(5)
//     [retires Bks0(t+1) (1 body old)]
// Tail index-clamped; vmcnt(0)+barrier drain before smem reuse as Ef.
// In-place R==Hout safe (block touches only its own 64 rows).
// ---------------------------------------------------------------------------
__global__ __launch_bounds__(512, 1)
void gemm_ln_k(const __hip_bfloat16* __restrict__ A,
               const __hip_bfloat16* __restrict__ WT,
               const float* __restrict__ bias,
               const float* R,                    // no restrict: aliases Hout
               const float* __restrict__ g,
               const float* __restrict__ be,
               float* Hout,                       // no restrict: aliases R
               __hip_bfloat16* __restrict__ Hb,
               int K) {
    __shared__ __align__(16) char smem[155648];
    const int tid  = threadIdx.x;
    const int lane = tid & 63;
    const int wave = tid >> 6;

    // XCD swizzle (grid = 256 = 32 per XCD, bijective)
    const int Lid = blockIdx.x;
    const int m0 = ((Lid & 7) * 32 + (Lid >> 3)) * 64;

    const int r = lane & 15, q = lane >> 4;
    const int qaB  = (q ^ ((r >> 1) & 3)) * 8;   // B de-swizzle (32-short rows)
    const int qaA0 = ((q)     ^ (r & 7)) * 8;    // A ks0 (64-short rows)
    const int qaA1 = ((4 + q) ^ (r & 7)) * 8;    // A ks1
    const int wn = wave * 64;                    // wave's 64-column slab

    // staging addresses (pre-swizzled sources, linear LDS dests)
    const int arow = tid >> 3;
    const int asb  = ((tid & 7) ^ ((tid >> 3) & 7)) * 8;
    const short* Ag = (const short*)A + (long)(m0 + arow) * K + asb;
    const int brow = tid >> 2;
    const int bsb  = ((tid & 3) ^ ((tid >> 3) & 3)) * 8;
    const short* Bg = (const short*)WT + (long)brow * K + bsb;
    const long brs = (long)128 * K;

    floatx4 acc[4][4];
    #pragma unroll
    for (int i = 0; i < 4; i++)
        #pragma unroll
        for (int j = 0; j < 4; j++) acc[i][j] = (floatx4)0.f;

    const int NTT = K >> 6;

    // prologue: [Bks0(0):4, A(0):1, A(1):1, Bks1(0):4] -> vmcnt(5)
    {
        const short* p0 = Bg;
        char* d0 = smem + 24576 + tid * 16;
        async16(p0, d0); async16(p0 + brs, d0 + 8192);
        async16(p0 + 2 * brs, d0 + 16384); async16(p0 + 3 * brs, d0 + 24576);
        async16(Ag, smem + tid * 16);                          // A(0) slot 0
        const int t1 = (1 < NTT) ? 1 : (NTT - 1);
        async16(Ag + (long)t1 * 64, smem + 8192 + tid * 16);   // A(1) slot 1
        const short* p1 = Bg + 32;
        char* d1 = smem + 24576 + 32768 + tid * 16;
        async16(p1, d1); async16(p1 + brs, d1 + 8192);
        async16(p1 + 2 * brs, d1 + 16384); async16(p1 + 3 * brs, d1 + 24576);
    }
    asm volatile("s_waitcnt vmcnt(5)" ::: "memory");  // Bks0(0)+A(0) landed
    __builtin_amdgcn_s_barrier();
    __builtin_amdgcn_sched_barrier(0);

    int slotR = 0;                    // t % 3
    for (int t = 0; t < NTT; ++t) {
        const short* As  = (const short*)(smem + slotR * 8192);
        const short* B0s = (const short*)(smem + 24576 + (t & 1) * 65536);
        const short* B1s = B0s + 16384;   // +32768 bytes
        const int tp1 = (t + 1 < NTT) ? t + 1 : NTT - 1;   // clamped
        const int tp2 = (t + 2 < NTT) ? t + 2 : NTT - 1;   // clamped
        int slotW = slotR + 2; if (slotW >= 3) slotW -= 3;  // (t+2)%3

        // ---- body A: ks0 ----
        {
            const short* p0 = Bg + (long)tp1 * 64;           // Bks0(t+1): 4
            char* d0 = smem + 24576 + ((t + 1) & 1) * 65536 + tid * 16;
            async16(p0, d0); async16(p0 + brs, d0 + 8192);
            async16(p0 + 2 * brs, d0 + 16384); async16(p0 + 3 * brs, d0 + 24576);
            async16(Ag + (long)tp2 * 64, smem + slotW * 8192 + tid * 16); // A(t+2)
        }
        {
            short8 a[4], b[4];
            #pragma unroll
            for (int mf = 0; mf < 4; mf++)
                a[mf] = *(const short8*)&As[(mf * 16 + r) * 64 + qaA0];
            #pragma unroll
            for (int nf = 0; nf < 4; nf++)
                b[nf] = *(const short8*)&B0s[(wn + nf * 16 + r) * 32 + qaB];
            #pragma unroll
            for (int mf = 0; mf < 4; mf++)
                #pragma unroll
                for (int nf = 0; nf < 4; nf++)
                    acc[mf][nf] = __builtin_amdgcn_mfma_f32_16x16x32_bf16(
                        a[mf], b[nf], acc[mf][nf], 0, 0, 0);
        }
        __builtin_amdgcn_sched_barrier(0);
        asm volatile("s_waitcnt vmcnt(5)" ::: "memory"); // A(t+1)+Bks1(t) in
        __builtin_amdgcn_s_barrier();
        __builtin_amdgcn_sched_barrier(0);

        // ---- body B: ks1 ----
        {
            const short* p1 = Bg + (long)tp1 * 64 + 32;      // Bks1(t+1): 4
            char* d1 = smem + 24576 + ((t + 1) & 1) * 65536 + 32768 + tid * 16;
            async16(p1, d1); async16(p1 + brs, d1 + 8192);
            async16(p1 + 2 * brs, d1 + 16384); async16(p1 + 3 * brs, d1 + 24576);
        }
        {
            short8 a[4], b[4];
            #pragma unroll
            for (int mf = 0; mf < 4; mf++)
                a[mf] = *(const short8*)&As[(mf * 16 + r) * 64 + qaA1];
            #pragma unroll
            for (int nf = 0; nf < 4; nf++)
                b[nf] = *(const short8*)&B1s[(wn + nf * 16 + r) * 32 + qaB];
            #pragma unroll
            for (int mf = 0; mf < 4; mf++)
                #pragma unroll
                for (int nf = 0; nf < 4; nf++)
                    acc[mf][nf] = __builtin_amdgcn_mfma_f32_16x16x32_bf16(
                        a[mf], b[nf], acc[mf][nf], 0, 0, 0);
        }
        __builtin_amdgcn_sched_barrier(0);
        asm volatile("s_waitcnt vmcnt(5)" ::: "memory"); // Bks0(t+1) in
        __builtin_amdgcn_s_barrier();
        __builtin_amdgcn_sched_barrier(0);

        slotR = slotR + 1; if (slotR >= 3) slotR -= 3;
    }

    // drain clamped tail loads before smem is reused as Ef
    asm volatile("s_waitcnt vmcnt(0)" ::: "memory");
    __builtin_amdgcn_s_barrier();
    __builtin_amdgcn_sched_barrier(0);

    // ---- fused epilogue: restage -> +bias+R -> row LN stats -> store ----
    // Ef[64][516] fp32 (132096B; writer rows q*4 spaced 2064 words = 16
    // banks -> 2-way max = free). stat after.
    float* Ef = (float*)smem;
    float* stat = (float*)(smem + 132096);
    const float gl = g[tid], bl = be[tid], bv = bias[tid];

    // write: wave w owns cols wn..wn+63 of ALL 64 rows (disjoint by column)
    #pragma unroll
    for (int mf = 0; mf < 4; mf++)
        #pragma unroll
        for (int nf = 0; nf < 4; nf++)
            #pragma unroll
            for (int rg = 0; rg < 4; rg++)
                Ef[(mf * 16 + q * 4 + rg) * 516 + wn + nf * 16 + r] =
                    acc[mf][nf][rg];
    __syncthreads();
    // bias + residual, coalesced (thread t owns column t of 64 rows)
    #pragma unroll 8
    for (int k = 0; k < 64; k++)
        Ef[k * 516 + tid] += bv + R[(long)(m0 + k) * 512 + tid];
    __syncthreads();
    // per-row stats: 8 threads per row, 64 cols each
    {
        const int row = tid >> 3, cc = tid & 7;
        float s = 0.f, ss = 0.f;
        #pragma unroll 8
        for (int j = 0; j < 64; j++) {
            const float v = Ef[row * 516 + cc + 8 * j];
            s += v; ss += v * v;
        }
        #pragma unroll
        for (int off = 1; off < 8; off <<= 1) {
            s  += __shfl_xor(s, off);
            ss += __shfl_xor(ss, off);
        }
        const float mu  = s * (1.0f / 512.0f);
        const float var = fmaxf(ss * (1.0f / 512.0f) - mu * mu, 0.f);
        const float inv = 1.0f / sqrtf(var + 1e-5f);
        if (cc == 0) { stat[row * 2] = mu; stat[row * 2 + 1] = inv; }
    }
    __syncthreads();
    // normalize + store, coalesced
    #pragma unroll 8
    for (int k = 0; k < 64; k++) {
        const float v  = Ef[k * 516 + tid];
        const float o  = (v - stat[k * 2]) * stat[k * 2 + 1] * gl + bl;
        const long idx = (long)(m0 + k) * 512 + tid;
        Hout[idx] = o;
        ((unsigned short*)Hb)[idx] = f2bf(o);
    }
}

// ---------------------------------------------------------------------------
// WT[l][n][k] = (bf16) W[l][k][n]
// ---------------------------------------------------------------------------
__global__ __launch_bounds__(256)
void transpose_cast_k(const float* __restrict__ W, __hip_bfloat16* __restrict__ WT,
                      int K, int N) {
    __shared__ float tile[32][33];
    const float* Wl = W + (long)blockIdx.z * K * N;
    __hip_bfloat16* WTl = WT + (long)blockIdx.z * K * N;
    const int n0 = blockIdx.x * 32, k0 = blockIdx.y * 32;
    const int tx = threadIdx.x & 31, ty = threadIdx.x >> 5;
    for (int rr = ty; rr < 32; rr += 8)
        tile[rr][tx] = Wl[(long)(k0 + rr) * N + n0 + tx];
    __syncthreads();
    for (int rr = ty; rr < 32; rr += 8)
        WTl[(long)(n0 + rr) * K + k0 + tx] = __float2bfloat16(tile[tx][rr]);
}

// ---------------------------------------------------------------------------
// fp32 tiled GEMM (in-proj only: M=16384, N=512, K=32)
// ---------------------------------------------------------------------------
template<int DO_GELU>
__global__ __launch_bounds__(256)
void gemm_bias_k(const float* __restrict__ A, long lda,
                 const float* __restrict__ W,
                 const float* __restrict__ bias,
                 float* __restrict__ C,
                 int M, int N, int K) {
    __shared__ float As[16][64];
    __shared__ float Ws[16][64];
    const int tx = threadIdx.x;
    const int ty = threadIdx.y;
    const int tid = ty * 16 + tx;
    const int m0 = blockIdx.y * 64;
    const int n0 = blockIdx.x * 64;
    float acc[4][4] = {};
    for (int k0 = 0; k0 < K; k0 += 16) {
        #pragma unroll
        for (int e = tid; e < 64 * 16; e += 256) {
            int m = e >> 4, k = e & 15;
            float v = 0.f;
            if (m0 + m < M) v = A[(long)(m0 + m) * lda + k0 + k];
            As[k][m] = v;
        }
        #pragma unroll
        for (int e = tid; e < 16 * 64; e += 256) {
            int k = e >> 6, n = e & 63;
            float v = 0.f;
            if (n0 + n < N) v = W[(long)(k0 + k) * N + n0 + n];
            Ws[k][n] = v;
        }
        __syncthreads();
        #pragma unroll
        for (int kk = 0; kk < 16; kk++) {
            float a[4], w[4];
            #pragma unroll
            for (int i = 0; i < 4; i++) a[i] = As[kk][ty * 4 + i];
            #pragma unroll
            for (int j = 0; j < 4; j++) w[j] = Ws[kk][tx * 4 + j];
            #pragma unroll
            for (int i = 0; i < 4; i++)
                #pragma unroll
                for (int j = 0; j < 4; j++)
                    acc[i][j] += a[i] * w[j];
        }
        __syncthreads();
    }
    #pragma unroll
    for (int i = 0; i < 4; i++) {
        int m = m0 + ty * 4 + i;
        if (m >= M) continue;
        #pragma unroll
        for (int j = 0; j < 4; j++) {
            int n = n0 + tx * 4 + j;
            if (n >= N) continue;
            float v = acc[i][j] + bias[n];
            if (DO_GELU) v = gelu_f(v);
            C[(long)m * N + n] = v;
        }
    }
}

// ---------------------------------------------------------------------------
// h = gelu(layernorm(X)) + pe ; also bf16 copy hb  (runs once)
// ---------------------------------------------------------------------------
__global__ __launch_bounds__(256)
void ln_gelu_pos_k(const float* __restrict__ X,
                   const float* __restrict__ g,
                   const float* __restrict__ be,
                   float* __restrict__ Hout,
                   __hip_bfloat16* __restrict__ Hb) {
    const int row = blockIdx.x;
    const int s = row & (S_ - 1);
    const int t = threadIdx.x;
    const float* x = X + (long)row * D_;
    float v0 = x[t], v1 = x[t + 256];
    __shared__ float red[256];
    red[t] = v0 + v1;
    __syncthreads();
    for (int off = 128; off; off >>= 1) {
        if (t < off) red[t] += red[t + off];
        __syncthreads();
    }
    float mu = red[0] * (1.0f / D_);
    __syncthreads();
    float d0 = v0 - mu, d1 = v1 - mu;
    red[t] = d0 * d0 + d1 * d1;
    __syncthreads();
    for (int off = 128; off; off >>= 1) {
        if (t < off) red[t] += red[t + off];
        __syncthreads();
    }
    float var = red[0] * (1.0f / D_);
    float inv = 1.0f / sqrtf(var + 1e-5f);
    float o0 = gelu_f(d0 * inv * g[t] + be[t]);
    float o1 = gelu_f(d1 * inv * g[t + 256] + be[t + 256]);
    {
        int d = t, i = d >> 1;
        float dv = expf((float)(2 * i) * (-9.210340371976184f / 512.0f));
        float ang = (float)s * dv;
        o0 += (d & 1) ? cosf(ang) : sinf(ang);
    }
    {
        int d = t + 256, i = d >> 1;
        float dv = expf((float)(2 * i) * (-9.210340371976184f / 512.0f));
        float ang = (float)s * dv;
        o1 += (d & 1) ? cosf(ang) : sinf(ang);
    }
    Hout[(long)row * D_ + t] = o0;
    Hout[(long)row * D_ + t + 256] = o1;
    Hb[(long)row * D_ + t] = __float2bfloat16(o0);
    Hb[(long)row * D_ + t + 256] = __float2bfloat16(o1);
}

// ---------------------------------------------------------------------------
// MFMA flash attention (verified structure, unchanged)
// ---------------------------------------------------------------------------
#define LDT 72
__global__ __launch_bounds__(256)
void attn_mfma_k(const __hip_bfloat16* __restrict__ qkv,
                 __hip_bfloat16* __restrict__ O) {
    const int qt = blockIdx.x;
    const int bh = blockIdx.y;
    const int b = bh >> 3, h = bh & (H_ - 1);
    const int tid = threadIdx.x;
    const int wave = tid >> 6, lane = tid & 63;
    const int ln = lane & 15, quad = lane >> 4;
    const int wm = wave * 32;
    const int i0 = qt * 128;

    __shared__ unsigned short Qs[128 * LDT];
    __shared__ unsigned short Ks[64 * LDT];
    __shared__ unsigned short Vt[64 * LDT];
    __shared__ unsigned short Ps[128 * LDT];
    __shared__ float stat[128];

    const unsigned short* base = (const unsigned short*)qkv + (long)b * S_ * (3 * D_);

    {
        const int r0 = tid >> 3, c0 = (tid & 7) * 8;
        #pragma unroll
        for (int i = 0; i < 4; i++) {
            const int rw = i * 32 + r0;
            *(short8*)&Qs[rw * LDT + c0] =
                *(const short8*)(base + (long)(i0 + rw) * (3 * D_) + h * HD_ + c0);
        }
    }

    float m_i[2] = { -INFINITY, -INFINITY };
    float l_i[2] = { 0.f, 0.f };
    floatx4 o_acc[2][4];
    #pragma unroll
    for (int i = 0; i < 2; i++)
        #pragma unroll
        for (int j = 0; j < 4; j++) o_acc[i][j] = (floatx4)0.f;

    const int kr = tid >> 2, kc = (tid & 3) * 16;
    const int vj = tid & 63, vc = (tid >> 6) * 16;

    const int ktmax = 2 * qt + 1;
    for (int kt = 0; kt <= ktmax; kt++) {
        const int j0 = kt * 64;
        {
            const unsigned short* kp = base + (long)(j0 + kr) * (3 * D_) + D_ + h * HD_ + kc;
            *(short8*)&Ks[kr * LDT + kc]     = *(const short8*)(kp);
            *(short8*)&Ks[kr * LDT + kc + 8] = *(const short8*)(kp + 8);
            const unsigned short* vp = base + (long)(j0 + vj) * (3 * D_) + 2 * D_ + h * HD_ + vc;
            short8 v0 = *(const short8*)(vp);
            short8 v1 = *(const short8*)(vp + 8);
            #pragma unroll
            for (int e = 0; e < 8; e++) {
                Vt[(vc + e) * LDT + vj]     = (unsigned short)v0[e];
                Vt[(vc + 8 + e) * LDT + vj] = (unsigned short)v1[e];
            }
        }
        __syncthreads();

        floatx4 sa[4][2];
        #pragma unroll
        for (int mt = 0; mt < 4; mt++)
            #pragma unroll
            for (int nt = 0; nt < 2; nt++) sa[mt][nt] = (floatx4)0.f;
        #pragma unroll
        for (int c = 0; c < 2; c++) {
            short8 kf[4], qf[2];
            #pragma unroll
            for (int mt = 0; mt < 4; mt++)
                kf[mt] = *(const short8*)&Ks[(mt * 16 + ln) * LDT + c * 32 + quad * 8];
            #pragma unroll
            for (int nt = 0; nt < 2; nt++)
                qf[nt] = *(const short8*)&Qs[(wm + nt * 16 + ln) * LDT + c * 32 + quad * 8];
            #pragma unroll
            for (int mt = 0; mt < 4; mt++)
                #pragma unroll
                for (int nt = 0; nt < 2; nt++)
                    sa[mt][nt] = __builtin_amdgcn_mfma_f32_16x16x32_bf16(
                        kf[mt], qf[nt], sa[mt][nt], 0, 0, 0);
        }

        const bool domask = (kt >= 2 * qt);
        #pragma unroll
        for (int nt = 0; nt < 2; nt++) {
            const int qg = i0 + wm + nt * 16 + ln;
            float mx = -INFINITY;
            #pragma unroll
            for (int mt = 0; mt < 4; mt++)
                #pragma unroll
                for (int rg = 0; rg < 4; rg++) {
                    float v = sa[mt][nt][rg] * 0.125f;
                    if (domask && (j0 + mt * 16 + quad * 4 + rg > qg)) v = -INFINITY;
                    sa[mt][nt][rg] = v;
                    mx = fmaxf(mx, v);
                }
            mx = fmaxf(mx, __shfl_xor(mx, 16));
            mx = fmaxf(mx, __shfl_xor(mx, 32));
            const float mn = fmaxf(m_i[nt], mx);
            const float alpha = __expf(m_i[nt] - mn);
            m_i[nt] = mn;
            float ls = 0.f;
            #pragma unroll
            for (int mt = 0; mt < 4; mt++) {
                ushort4 pk;
                float p0 = __expf(sa[mt][nt][0] - mn);
                float p1 = __expf(sa[mt][nt][1] - mn);
                float p2 = __expf(sa[mt][nt][2] - mn);
                float p3 = __expf(sa[mt][nt][3] - mn);
                ls += p0 + p1 + p2 + p3;
                pk.x = f2bf(p0); pk.y = f2bf(p1); pk.z = f2bf(p2); pk.w = f2bf(p3);
                *(ushort4*)&Ps[(wm + nt * 16 + ln) * LDT + mt * 16 + quad * 4] = pk;
            }
            ls += __shfl_xor(ls, 16);
            ls += __shfl_xor(ls, 32);
            l_i[nt] = l_i[nt] * alpha + ls;
            if (quad == 0) stat[wm + nt * 16 + ln] = alpha;
        }

        #pragma unroll
        for (int mt2 = 0; mt2 < 2; mt2++) {
            #pragma unroll
            for (int rg = 0; rg < 4; rg++) {
                const float a = stat[wm + mt2 * 16 + quad * 4 + rg];
                #pragma unroll
                for (int nt = 0; nt < 4; nt++) o_acc[mt2][nt][rg] *= a;
            }
        }

        #pragma unroll
        for (int c = 0; c < 2; c++) {
            short8 pf[2], vf[4];
            #pragma unroll
            for (int mt2 = 0; mt2 < 2; mt2++)
                pf[mt2] = *(const short8*)&Ps[(wm + mt2 * 16 + ln) * LDT + c * 32 + quad * 8];
            #pragma unroll
            for (int nt = 0; nt < 4; nt++)
                vf[nt] = *(const short8*)&Vt[(nt * 16 + ln) * LDT + c * 32 + quad * 8];
            #pragma unroll
            for (int mt2 = 0; mt2 < 2; mt2++)
                #pragma unroll
                for (int nt = 0; nt < 4; nt++)
                    o_acc[mt2][nt] = __builtin_amdgcn_mfma_f32_16x16x32_bf16(
                        pf[mt2], vf[nt], o_acc[mt2][nt], 0, 0, 0);
        }
        __syncthreads();
    }

    if (quad == 0) {
        stat[wm + ln]      = l_i[0];
        stat[wm + 16 + ln] = l_i[1];
    }
    unsigned short* Og = (unsigned short*)O;
    #pragma unroll
    for (int mt2 = 0; mt2 < 2; mt2++) {
        #pragma unroll
        for (int rg = 0; rg < 4; rg++) {
            const float linv = 1.0f / stat[wm + mt2 * 16 + quad * 4 + rg];
            const long row = (long)(b * S_ + i0 + wm + mt2 * 16 + quad * 4 + rg);
            #pragma unroll
            for (int nt = 0; nt < 4; nt++)
                Og[row * D_ + h * HD_ + nt * 16 + ln] =
                    f2bf(o_acc[mt2][nt][rg] * linv);
        }
    }
}

// ---------------------------------------------------------------------------
// Head kernels
// ---------------------------------------------------------------------------
__global__ __launch_bounds__(256)
void head1_k(const float* __restrict__ h, const float* __restrict__ w1,
             const float* __restrict__ b1, float* __restrict__ th) {
    __shared__ float hs[D_];
    const int b = blockIdx.x, n = threadIdx.x;
    const float* hr = h + (long)(b * S_ + S_ - 1) * D_;
    hs[n] = hr[n];
    hs[n + 256] = hr[n + 256];
    __syncthreads();
    float s = 0.f;
    #pragma unroll 8
    for (int k = 0; k < D_; k++) s += hs[k] * w1[(long)k * 256 + n];
    th[b * 256 + n] = gelu_f(s + b1[n]);
}

__global__ __launch_bounds__(64)
void head2_k(const float* __restrict__ th, const float* __restrict__ w2,
             const float* __restrict__ b2, float* __restrict__ out) {
    const int b = blockIdx.x, lane = threadIdx.x;
    const float* t = th + b * 256;
    float s0 = 0.f, s1 = 0.f, s2 = 0.f;
    #pragma unroll
    for (int e = 0; e < 4; e++) {
        const int k = lane * 4 + e;
        const float tv = t[k];
        s0 += tv * w2[k * 3 + 0];
        s1 += tv * w2[k * 3 + 1];
        s2 += tv * w2[k * 3 + 2];
    }
    #pragma unroll
    for (int off = 1; off < 64; off <<= 1) {
        s0 += __shfl_xor(s0, off);
        s1 += __shfl_xor(s1, off);
        s2 += __shfl_xor(s2, off);
    }
    if (lane == 0) {
        out[b * 3 + 0] = s0 + b2[0];
        out[b * 3 + 1] = s1 + b2[1];
        out[b * 3 + 2] = s2 + b2[2];
    }
}

// ---------------------------------------------------------------------------
extern "C" void kernel_launch(void* const* d_in, const int* in_sizes, int n_in,
                              void* d_out, int out_size, void* d_ws, size_t ws_size,
                              hipStream_t stream) {
    const float* x     = (const float*)d_in[0];
    const float* w_in  = (const float*)d_in[1];
    const float* b_in  = (const float*)d_in[2];
    const float* g_in  = (const float*)d_in[3];
    const float* be_in = (const float*)d_in[4];
    const float* w_qkv = (const float*)d_in[5];
    const float* b_qkv = (const float*)d_in[6];
    const float* w_out = (const float*)d_in[7];
    const float* b_out = (const float*)d_in[8];
    const float* g1    = (const float*)d_in[9];
    const float* be1   = (const float*)d_in[10];
    const float* w_ff1 = (const float*)d_in[11];
    const float* b_ff1 = (const float*)d_in[12];
    const float* w_ff2 = (const float*)d_in[13];
    const float* b_ff2 = (const float*)d_in[14];
    const float* g2    = (const float*)d_in[15];
    const float* be2   = (const float*)d_in[16];
    const float* w_h1  = (const float*)d_in[17];
    const float* b_h1  = (const float*)d_in[18];
    const float* w_h2  = (const float*)d_in[19];
    const float* b_h2  = (const float*)d_in[20];
    float* out = (float*)d_out;

    float* h    = (float*)d_ws;
    float* bufB = h + (long)M_ * D_;
    float* th   = bufB + (long)M_ * D_;
    __hip_bfloat16* hb    = (__hip_bfloat16*)(th + 32 * 256);
    __hip_bfloat16* attb  = hb + (long)M_ * D_;
    __hip_bfloat16* bufAb = attb + (long)M_ * D_;
    __hip_bfloat16* qkvT  = bufAb + (long)M_ * FF_;
    __hip_bfloat16* outT  = qkvT + (long)L_ * (3 * D_) * D_;
    __hip_bfloat16* ff1T  = outT + (long)L_ * D_ * D_;
    __hip_bfloat16* ff2T  = ff1T + (long)L_ * FF_ * D_;

    dim3 blk(16, 16);

    transpose_cast_k<<<dim3((3 * D_) / 32, D_ / 32, L_), 256, 0, stream>>>(w_qkv, qkvT, D_, 3 * D_);
    transpose_cast_k<<<dim3(D_ / 32, D_ / 32, L_), 256, 0, stream>>>(w_out, outT, D_, D_);
    transpose_cast_k<<<dim3(FF_ / 32, D_ / 32, L_), 256, 0, stream>>>(w_ff1, ff1T, D_, FF_);
    transpose_cast_k<<<dim3(D_ / 32, FF_ / 32, L_), 256, 0, stream>>>(w_ff2, ff2T, FF_, D_);

    gemm_bias_k<0><<<dim3(D_ / 64, M_ / 64), blk, 0, stream>>>(
        x, IN_, w_in, b_in, bufB, M_, D_, IN_);
    ln_gelu_pos_k<<<M_, 256, 0, stream>>>(bufB, g_in, be_in, h, hb);

    for (int l = 0; l < L_; l++) {
        // qkv -> bf16 bufAb (128^2 counted-vmcnt, 1536 blocks)
        gemm_mfma_k<0, 1, 0><<<dim3((3 * D_) / 128, M_ / 128), 256, 0, stream>>>(
            hb, qkvT + (long)l * (3 * D_) * D_, b_qkv + l * 3 * D_, nullptr,
            bufAb, 3 * D_, D_);
        attn_mfma_k<<<dim3(S_ / 128, B_ * H_), 256, 0, stream>>>(bufAb, attb);
        // fused: h = LN(attb @ outT + b_out + h)  (writes h fp32 + hb bf16)
        gemm_ln_k<<<256, 512, 0, stream>>>(
            attb, outT + (long)l * D_ * D_, b_out + l * D_, h,
            g1 + l * D_, be1 + l * D_, h, hb, D_);
        // ff1 -> bf16 bufAb (gelu)  (128^2 counted-vmcnt, 2048 blocks, 2/CU)
        gemm_mfma_k<1, 1, 0><<<dim3(FF_ / 128, M_ / 128), 256, 0, stream>>>(
            hb, ff1T + (long)l * FF_ * D_, b_ff1 + l * FF_, nullptr,
            bufAb, FF_, D_);
        // fused: h = LN(bufAb @ ff2T + b_ff2 + h)
        gemm_ln_k<<<256, 512, 0, stream>>>(
            bufAb, ff2T + (long)l * D_ * FF_, b_ff2 + l * D_, h,
            g2 + l * D_, be2 + l * D_, h, hb, FF_);
    }

    head1_k<<<B_, 256, 0, stream>>>(h, w_h1, b_h1, th);
    head2_k<<<B_, 64, 0, stream>>>(th, w_h2, b_h2, out);
}